// Round 1
// baseline (2917.658 us; speedup 1.0000x reference)
//
#include <hip/hip_runtime.h>

#define BB 256
#define TT 256
#define NN 512
#define HH 512
#define G4H 2048   // 4*H
#define K2 1024    // N + H combined K

typedef short short8 __attribute__((ext_vector_type(8)));
typedef float f32x4 __attribute__((ext_vector_type(4)));

static __device__ __forceinline__ ushort f2bf(float f) {
  uint b = __builtin_bit_cast(uint, f);
  b += 0x7FFFu + ((b >> 16) & 1u);
  return (ushort)(b >> 16);
}

static __device__ __forceinline__ float sigmoidf_(float x) {
  return 1.0f / (1.0f + expf(-x));
}

// ---------------------------------------------------------------------------
// Prep: W2 = [w_ih | w_hh] as bf16 (2048 x 1024), b_gate = b_ih + b_hh,
// copy h0 -> hbuf0, c0 -> cbuf.
// grid 8192 x 256 covers 2048*1024 = 2,097,152 threads exactly.
// ---------------------------------------------------------------------------
__global__ __launch_bounds__(256) void prep_kernel(
    const float* __restrict__ w_ih, const float* __restrict__ w_hh,
    const float* __restrict__ b_ih, const float* __restrict__ b_hh,
    const float* __restrict__ h0, const float* __restrict__ c0,
    ushort* __restrict__ W2, float* __restrict__ bgate,
    float* __restrict__ hinit, float* __restrict__ cinit) {
  int idx = blockIdx.x * 256 + threadIdx.x;
  if (idx < G4H * K2) {
    int row = idx >> 10;
    int k = idx & 1023;
    float v = (k < NN) ? w_ih[row * NN + k] : w_hh[row * HH + (k - NN)];
    W2[idx] = f2bf(v);
  }
  if (idx < G4H) bgate[idx] = b_ih[idx] + b_hh[idx];
  if (idx < BB * HH) {
    hinit[idx] = h0[idx];
    cinit[idx] = c0[idx];
  }
}

// ---------------------------------------------------------------------------
// Attention: proj_x[b,n] = sum_t x[b,t,n]*w_x[t]; a = softmax_n(proj_x).
// Softmax is shift-invariant, so the h/c/bias terms drop out and a is the
// SAME for all timesteps. Write a to ws and broadcast to attentions output.
// grid 256 (one block per b), block 256 threads (each owns n=tid, n=tid+256).
// ---------------------------------------------------------------------------
__global__ __launch_bounds__(256) void attn_kernel(
    const float* __restrict__ x, const float* __restrict__ attn_w,
    float* __restrict__ a_out, float* __restrict__ attn_out) {
  __shared__ float wx[TT];
  __shared__ float red[8];
  const int b = blockIdx.x;
  const int tid = threadIdx.x;
  wx[tid] = attn_w[2 * HH + tid];
  __syncthreads();

  const float* xb = x + (size_t)b * TT * NN;
  float p0 = 0.0f, p1 = 0.0f;
  for (int t = 0; t < TT; ++t) {
    float w = wx[t];
    p0 += xb[t * NN + tid] * w;
    p1 += xb[t * NN + 256 + tid] * w;
  }

  const int lane = tid & 63, wv = tid >> 6;
  float m = fmaxf(p0, p1);
  #pragma unroll
  for (int o = 32; o; o >>= 1) m = fmaxf(m, __shfl_xor(m, o));
  if (lane == 0) red[wv] = m;
  __syncthreads();
  m = fmaxf(fmaxf(red[0], red[1]), fmaxf(red[2], red[3]));
  float e0 = expf(p0 - m), e1 = expf(p1 - m);
  float s = e0 + e1;
  #pragma unroll
  for (int o = 32; o; o >>= 1) s += __shfl_xor(s, o);
  if (lane == 0) red[4 + wv] = s;
  __syncthreads();
  s = red[4] + red[5] + red[6] + red[7];
  float inv = 1.0f / s;
  float a0 = e0 * inv, a1 = e1 * inv;
  a_out[b * NN + tid] = a0;
  a_out[b * NN + 256 + tid] = a1;

  float* ob = attn_out + (size_t)b * TT * NN;
  for (int t = 0; t < TT; ++t) {
    ob[t * NN + tid] = a0;
    ob[t * NN + 256 + tid] = a1;
  }
}

// ---------------------------------------------------------------------------
// One LSTM step. gates(B x 2048) = [a*x_t | h] (B x 1024) @ W2^T + b_gate.
// grid 256 = 16 batch-groups x 16 j-tiles. block 256 threads = 4 waves.
// Block output tile: 16 batches x 128 rows {g*512 + jt*32 + jj, g=0..3}.
// Wave g computes gate chunk g (16 x 32) via mfma_f32_16x16x32_bf16.
// LDS tiles XOR-swizzled at 16B granularity: granule ^= (row & 7).
// ---------------------------------------------------------------------------
__global__ __launch_bounds__(256) void step_kernel(
    const float* __restrict__ x,      // (B,T,N)
    const float* __restrict__ a,      // (B,N)
    const ushort* __restrict__ W2,    // (2048,1024) bf16
    const float* __restrict__ bgate,  // (2048)
    const float* __restrict__ hin,    // (B,H)
    float* __restrict__ hout,         // (B,H)
    float* __restrict__ cbuf,         // (B,H)
    float* __restrict__ enc,          // (B,T,H) output 2
    int t) {
  __shared__ ushort Alds[16 * 128];       // 4 KB  (16 x 128 bf16, swizzled)
  __shared__ ushort Blds[128 * 128];      // 32 KB (128 x 128 bf16, swizzled)
  __shared__ float ex[4][16][32];         // 8 KB  [gate][b][jj]

  const int tid = threadIdx.x;
  const int lane = tid & 63;
  const int wid = tid >> 6;               // gate chunk 0..3
  const int bg = blockIdx.x >> 4;         // batch group 0..15
  const int jt = blockIdx.x & 15;         // j tile 0..15

  const int srow = tid >> 4;              // staging row 0..15
  const int sg = tid & 15;                // staging 16B granule 0..15

  f32x4 acc0 = {0.f, 0.f, 0.f, 0.f};
  f32x4 acc1 = {0.f, 0.f, 0.f, 0.f};

  for (int kc = 0; kc < 8; ++kc) {        // K chunks of 128
    // ---- stage A (16 x 128): a*x_t for kc<4, h for kc>=4 ----
    {
      const int gb = bg * 16 + srow;
      const int k0 = sg * 8;
      float v[8];
      if (kc < 4) {
        const int n = kc * 128 + k0;
        const float4 x0 = *(const float4*)(x + ((size_t)gb * TT + t) * NN + n);
        const float4 x1 = *(const float4*)(x + ((size_t)gb * TT + t) * NN + n + 4);
        const float4 a0 = *(const float4*)(a + gb * NN + n);
        const float4 a1 = *(const float4*)(a + gb * NN + n + 4);
        v[0] = x0.x * a0.x; v[1] = x0.y * a0.y; v[2] = x0.z * a0.z; v[3] = x0.w * a0.w;
        v[4] = x1.x * a1.x; v[5] = x1.y * a1.y; v[6] = x1.z * a1.z; v[7] = x1.w * a1.w;
      } else {
        const int n = (kc - 4) * 128 + k0;
        const float4 h0v = *(const float4*)(hin + gb * HH + n);
        const float4 h1v = *(const float4*)(hin + gb * HH + n + 4);
        v[0] = h0v.x; v[1] = h0v.y; v[2] = h0v.z; v[3] = h0v.w;
        v[4] = h1v.x; v[5] = h1v.y; v[6] = h1v.z; v[7] = h1v.w;
      }
      uint4 pk;
      pk.x = (uint)f2bf(v[0]) | ((uint)f2bf(v[1]) << 16);
      pk.y = (uint)f2bf(v[2]) | ((uint)f2bf(v[3]) << 16);
      pk.z = (uint)f2bf(v[4]) | ((uint)f2bf(v[5]) << 16);
      pk.w = (uint)f2bf(v[6]) | ((uint)f2bf(v[7]) << 16);
      *(uint4*)&Alds[srow * 128 + ((sg ^ (srow & 7)) << 3)] = pk;
    }
    // ---- stage B (128 x 128): W2 rows for this block's 128 gate-rows ----
    #pragma unroll
    for (int rr = 0; rr < 8; ++rr) {
      const int lr = rr * 16 + srow;                   // 0..127
      const int gate = lr >> 5, jj = lr & 31;
      const int grow = gate * 512 + jt * 32 + jj;      // W2 row
      const uint4 w = *(const uint4*)(W2 + (size_t)grow * K2 + kc * 128 + sg * 8);
      *(uint4*)&Blds[lr * 128 + ((sg ^ (lr & 7)) << 3)] = w;
    }
    __syncthreads();
    // ---- MFMA: 4 k-steps of 32 ----
    {
      const int arow = lane & 15;
      const int kq = lane >> 4;
      #pragma unroll
      for (int ks = 0; ks < 4; ++ks) {
        const int ag = ks * 4 + kq;                    // granule within row
        short8 af = *(const short8*)&Alds[arow * 128 + ((ag ^ (arow & 7)) << 3)];
        const int br0 = wid * 32 + arow;
        const int br1 = br0 + 16;
        short8 bf0 = *(const short8*)&Blds[br0 * 128 + ((ag ^ (br0 & 7)) << 3)];
        short8 bf1 = *(const short8*)&Blds[br1 * 128 + ((ag ^ (br1 & 7)) << 3)];
        acc0 = __builtin_amdgcn_mfma_f32_16x16x32_bf16(af, bf0, acc0, 0, 0, 0);
        acc1 = __builtin_amdgcn_mfma_f32_16x16x32_bf16(af, bf1, acc1, 0, 0, 0);
      }
    }
    __syncthreads();
  }

  // ---- exchange gate tiles: C layout col=lane&15 (jj), row=(lane>>4)*4+e (b)
  {
    const int c = lane & 15;
    const int rb = (lane >> 4) << 2;
    #pragma unroll
    for (int e = 0; e < 4; ++e) {
      ex[wid][rb + e][c] = acc0[e];
      ex[wid][rb + e][c + 16] = acc1[e];
    }
  }
  __syncthreads();

  // ---- elementwise LSTM: 512 outputs, 2 per thread ----
  #pragma unroll
  for (int q = 0; q < 2; ++q) {
    const int idx = tid + q * 256;
    const int b = idx >> 5;              // 0..15
    const int jj = idx & 31;
    const int col = jt * 32 + jj;        // 0..511
    float ig = ex[0][b][jj] + bgate[0 * 512 + col];
    float fg = ex[1][b][jj] + bgate[1 * 512 + col];
    float gg = ex[2][b][jj] + bgate[2 * 512 + col];
    float og = ex[3][b][jj] + bgate[3 * 512 + col];
    ig = sigmoidf_(ig);
    fg = sigmoidf_(fg);
    gg = tanhf(gg);
    og = sigmoidf_(og);
    const int gb = bg * 16 + b;
    const size_t ci = (size_t)gb * HH + col;
    const float c_old = cbuf[ci];
    const float cn = fg * c_old + ig * gg;
    const float hn = og * tanhf(cn);
    cbuf[ci] = cn;
    hout[ci] = hn;
    enc[((size_t)gb * TT + t) * HH + col] = hn;
  }
}

extern "C" void kernel_launch(void* const* d_in, const int* in_sizes, int n_in,
                              void* d_out, int out_size, void* d_ws, size_t ws_size,
                              hipStream_t stream) {
  const float* x      = (const float*)d_in[0];  // (B,T,N)
  const float* h0     = (const float*)d_in[1];  // (B,H)
  const float* c0     = (const float*)d_in[2];  // (B,H)
  const float* attn_w = (const float*)d_in[3];  // (2H+T)
  // d_in[4] = attn_b: scalar, softmax-shift-invariant -> unused
  const float* w_ih   = (const float*)d_in[5];  // (4H,N)
  const float* w_hh   = (const float*)d_in[6];  // (4H,H)
  const float* b_ih   = (const float*)d_in[7];  // (4H)
  const float* b_hh   = (const float*)d_in[8];  // (4H)

  float* attn_out = (float*)d_out;                          // (B,T,N)
  float* enc_out  = (float*)d_out + (size_t)BB * TT * NN;   // (B,T,H)

  // workspace carve (all 16B aligned), total ~6.3 MB
  char* ws = (char*)d_ws;
  float*  a_ws   = (float*)(ws);                        // 256*512 f32 = 512 KB
  ushort* W2_ws  = (ushort*)(ws + 524288);              // 2048*1024 bf16 = 4 MB
  float*  bg_ws  = (float*)(ws + 524288 + 4194304);     // 2048 f32 = 8 KB
  float*  hbuf0  = (float*)(ws + 524288 + 4194304 + 8192);
  float*  hbuf1  = (float*)(ws + 524288 + 4194304 + 8192 + 524288);
  float*  cbuf   = (float*)(ws + 524288 + 4194304 + 8192 + 1048576);

  prep_kernel<<<8192, 256, 0, stream>>>(w_ih, w_hh, b_ih, b_hh, h0, c0,
                                        W2_ws, bg_ws, hbuf0, cbuf);
  attn_kernel<<<BB, 256, 0, stream>>>(x, attn_w, a_ws, attn_out);

  for (int t = 0; t < TT; ++t) {
    const float* hin = (t & 1) ? hbuf1 : hbuf0;
    float* hout      = (t & 1) ? hbuf0 : hbuf1;
    step_kernel<<<256, 256, 0, stream>>>(x, a_ws, W2_ws, bg_ws,
                                         hin, hout, cbuf, enc_out, t);
  }
}